// Round 1
// baseline (139.163 us; speedup 1.0000x reference)
//
#include <hip/hip_runtime.h>

// Hapke BRDF — elementwise over N=1M points.
// Inputs (setup_inputs order, all float32):
//  0 pts2l (N,1,3)  1 pts2c (N,3)  2 normal (N,3)  3 w (N,3)  4 b (N,3)
//  5 c (N,3)  6 theta (N,)  7 h (N,1)  8 B0 (N,1)
// Output: brdf (N,3) float32.
// Traffic: 21 in + 3 out floats/point = 96 MB -> HBM-bound floor ~15 us.

#define EPSF 1e-5f
#define PIF  3.14159265358979323846f

__device__ __forceinline__ float nz(float y, float rep) { return (y != y) ? rep : y; }
__device__ __forceinline__ float clamp1(float x) { return fminf(fmaxf(x, -1.0f), 1.0f); }

__global__ __launch_bounds__(256)
void hapke_kernel(const float* __restrict__ pts2l, const float* __restrict__ pts2c,
                  const float* __restrict__ normal, const float* __restrict__ w,
                  const float* __restrict__ b, const float* __restrict__ c,
                  const float* __restrict__ theta, const float* __restrict__ h,
                  const float* __restrict__ B0, float* __restrict__ out, int N)
{
    int idx = blockIdx.x * blockDim.x + threadIdx.x;
    if (idx >= N) return;
    const int i3 = idx * 3;

    float lx = pts2l[i3], ly = pts2l[i3+1], lz = pts2l[i3+2];
    float vx = pts2c[i3], vy = pts2c[i3+1], vz = pts2c[i3+2];
    float nx = normal[i3], ny = normal[i3+1], nzc = normal[i3+2];

    float ci  = clamp1(nx*lx + ny*ly + nzc*lz);
    float sza = acosf(ci);
    float si  = sinf(sza);
    float cv  = clamp1(nx*vx + ny*vy + nzc*vz);
    float vza = acosf(cv);
    float sv  = sinf(vza);
    float cg  = clamp1(lx*vx + ly*vy + lz*vz);
    float g   = acosf(cg);
    float cphi = clamp1((cg - ci*cv) / (si*sv + 1e-8f));
    float phi  = acosf(cphi);

    float th = theta[idx];
    float tan_th_e = tanf(th + EPSF);          // tan(theta+EPS) — used by chi/E1/E2/eta
    float cot_th   = 1.0f / tan_th_e;
    float cot_i    = 1.0f / tanf(sza + EPSF);
    float cot_e    = 1.0f / tanf(vza + EPSF);

    float E1i = nz(expf(-(2.0f/PIF) * cot_th * cot_i), 0.0f);
    float E1e = nz(expf(-(2.0f/PIF) * cot_th * cot_e), 0.0f);
    float ct2 = cot_th * cot_th;
    float E2i = nz(expf(-(1.0f/PIF) * ct2 * cot_i*cot_i), 0.0f);
    float E2e = nz(expf(-(1.0f/PIF) * ct2 * cot_e*cot_e), 0.0f);

    float chit = nz(1.0f / sqrtf(1.0f + PIF * tan_th_e * tan_th_e), 0.0f);
    // _eta: cos(sza)=ci, sin(sza)=si (identical after clamp)
    float etai = nz(chit * (ci + si * tan_th_e * (E2i / (2.0f - E1i))), 0.0f);
    float etae = nz(chit * (cv + sv * tan_th_e * (E2e / (2.0f - E1e))), 0.0f);

    float sp  = sinf(0.5f * phi);
    float sp2 = sp * sp;
    float tan_th = tanf(th);                   // NOTE: _mu_eff/_mu0_eff use tan(th), no EPS
    bool  ile = (sza <= vza);
    float phi_pi = phi * (1.0f / PIF);
    float d1 = 2.0f - E1e - phi_pi * E1i;
    float d2 = 2.0f - E1i - phi_pi * E1e;
    // cos(phi) == cphi after clamp round-trip
    float ymu  = ile ? (E2e - sp2*E2i) / d1 : (cphi*E2i + sp2*E2e) / d2;
    float cv_e = nz(chit * (cv + sv * tan_th * ymu), cv);     // _mu_eff
    float ymu0 = ile ? (cphi*E2e + sp2*E2i) / d1 : (E2i - sp2*E2e) / d2;
    float ci_e = nz(chit * (ci + si * tan_th * ymu0), ci);    // _mu0_eff

    // _S (shadowing)
    float ff = nz(expf(-2.0f * tanf(0.5f * (phi + EPSF))), 0.0f);
    float ci_etai = ci / etai;
    float cv_etae = cv / etae;
    float temp = (cv_e / etae) * ci_etai * chit;
    float shad = ile ? temp / (1.0f - ff + ff * chit * ci_etai)
                     : temp / (1.0f - ff + ff * chit * cv_etae);
    shad = nz(shad, 0.0f);

    float B = B0[idx] / (1.0f + (1.0f / h[idx]) * tanf(0.5f * g)) + 1.0f;
    float tmp1 = ci_e / (ci_e + cv_e) / ci;    // cos(sza)=ci

    // _HF log term depends only on row scalars -> hoist out of channel loop
    float logi = logf(fabsf((1.0f + ci_e) / ci_e));
    float loge = logf(fabsf((1.0f + cv_e) / cv_e));

    #pragma unroll
    for (int k = 0; k < 3; ++k) {
        float wk = w[i3+k], bk = b[i3+k], ck = c[i3+k];
        // _PF: pow(t,1.5) = t*sqrt(t); t>0 always since b in [0,0.8)
        float b2 = bk * bk;
        float bx = bk * cg;
        float t1 = 1.0f - 2.0f*bx + b2;
        float t2 = 1.0f + 2.0f*bx + b2;
        float omb2 = 1.0f - b2;
        float P = nz(ck * omb2 / (t1 * sqrtf(t1) + 1e-6f)
                   + (1.0f - ck) * omb2 / (t2 * sqrtf(t2) + 1e-6f), 0.0f);
        // _HF
        float gamma = sqrtf(1.0f - wk);
        float ro = (1.0f - gamma) / (1.0f + gamma);
        float Hi = nz(1.0f / (1.0f - wk*ci_e*(ro + (1.0f - 2.0f*ro*ci_e)*0.5f*logi)), 1.0f);
        float Hv = nz(1.0f / (1.0f - wk*cv_e*(ro + (1.0f - 2.0f*ro*cv_e)*0.5f*loge)), 1.0f);
        float tmp2 = P * B + Hi * Hv - 1.0f;
        out[i3+k] = wk * 0.25f * tmp1 * tmp2 * shad;   // w/HPK_SCL, HPK_SCL=4
    }
}

extern "C" void kernel_launch(void* const* d_in, const int* in_sizes, int n_in,
                              void* d_out, int out_size, void* d_ws, size_t ws_size,
                              hipStream_t stream) {
    const float* pts2l  = (const float*)d_in[0];
    const float* pts2c  = (const float*)d_in[1];
    const float* normal = (const float*)d_in[2];
    const float* w      = (const float*)d_in[3];
    const float* b      = (const float*)d_in[4];
    const float* c      = (const float*)d_in[5];
    const float* theta  = (const float*)d_in[6];
    const float* h      = (const float*)d_in[7];
    const float* B0     = (const float*)d_in[8];
    float* out = (float*)d_out;

    int N = in_sizes[6];                // theta is (N,)
    const int block = 256;
    int grid = (N + block - 1) / block;
    hapke_kernel<<<grid, block, 0, stream>>>(pts2l, pts2c, normal, w, b, c,
                                             theta, h, B0, out, N);
}

// Round 2
// 124.775 us; speedup vs baseline: 1.1153x; 1.1153x over previous
//
#include <hip/hip_runtime.h>

// Hapke BRDF — elementwise, N=1M. R2: VALU-bound (77.8% VALUBusy, HBM 17%).
// Replace libm tanf/acosf/sinf with trig identities + native v_sin/v_cos/v_exp/
// v_log/v_rcp/v_sqrt. Threshold slack is huge (0.71 vs 3.18) — fast math is safe.

#define PIF  3.14159265358979323846f
#define EPSF 1e-5f

__device__ __forceinline__ float rcp(float x)  { return __builtin_amdgcn_rcpf(x); }
__device__ __forceinline__ float rsq(float x)  { return __builtin_amdgcn_rsqf(x); }
__device__ __forceinline__ float sqf(float x)  { return __builtin_amdgcn_sqrtf(x); }
__device__ __forceinline__ float nz(float y, float r) { return (y != y) ? r : y; }
__device__ __forceinline__ float clamp1(float x) { return fminf(fmaxf(x, -1.0f), 1.0f); }
// fast tan via native sin/cos (v_sin_f32 / v_cos_f32); args here are in [0, ~pi/2+eps]
__device__ __forceinline__ float ftan(float x) { return __sinf(x) * rcp(__cosf(x)); }

__global__ __launch_bounds__(256)
void hapke_kernel(const float* __restrict__ pts2l, const float* __restrict__ pts2c,
                  const float* __restrict__ normal, const float* __restrict__ w,
                  const float* __restrict__ b, const float* __restrict__ c,
                  const float* __restrict__ theta, const float* __restrict__ h,
                  const float* __restrict__ B0, float* __restrict__ out, int N)
{
    int idx = blockIdx.x * blockDim.x + threadIdx.x;
    if (idx >= N) return;
    const int i3 = idx * 3;

    float lx = pts2l[i3], ly = pts2l[i3+1], lz = pts2l[i3+2];
    float vx = pts2c[i3], vy = pts2c[i3+1], vz = pts2c[i3+2];
    float nx = normal[i3], ny = normal[i3+1], nzc = normal[i3+2];

    // ci, cv in [0,1] by construction (l,v flipped into normal's hemisphere)
    float ci = clamp1(nx*lx + ny*ly + nzc*lz);
    float cv = clamp1(nx*vx + ny*vy + nzc*vz);
    float cg = clamp1(lx*vx + ly*vy + lz*vz);
    float si = sqf(1.0f - ci*ci);            // sin(acos(ci)) — exact identity
    float sv = sqf(1.0f - cv*cv);
    float cphi = clamp1((cg - ci*cv) * rcp(si*sv + 1e-8f));
    float phi  = acosf(cphi);                // needed for phi/PI — the one acos kept

    float th = theta[idx];
    float t  = ftan(th + EPSF);              // shared for tan(th+EPS) and tan(th): diff <= 2e-5
    float cot_th = rcp(t);
    float cot_i  = ci * rcp(si);             // cot(sza); si=0 -> +inf -> E*=0 (matches ref limit)
    float cot_e  = cv * rcp(sv);

    float E1i = nz(__expf(-(2.0f/PIF) * cot_th * cot_i), 0.0f);
    float E1e = nz(__expf(-(2.0f/PIF) * cot_th * cot_e), 0.0f);
    float ct2 = cot_th * cot_th;
    float E2i = nz(__expf(-(1.0f/PIF) * ct2 * cot_i*cot_i), 0.0f);
    float E2e = nz(__expf(-(1.0f/PIF) * ct2 * cot_e*cot_e), 0.0f);

    float chit = rsq(1.0f + PIF * t * t);    // always finite for th in [0.05,0.55]
    float etai = nz(chit * (ci + si * t * (E2i * rcp(2.0f - E1i))), 0.0f);
    float etae = nz(chit * (cv + sv * t * (E2e * rcp(2.0f - E1e))), 0.0f);

    float sp2 = 0.5f * (1.0f - cphi);        // sin^2(phi/2) — exact half-angle identity
    bool  ile = (ci >= cv);                  // sza <= vza  (acos decreasing; branches continuous at tie)
    float phi_pi = phi * (1.0f / PIF);
    float rd1 = rcp(2.0f - E1e - phi_pi * E1i);
    float rd2 = rcp(2.0f - E1i - phi_pi * E1e);
    float ymu  = ile ? (E2e - sp2*E2i) * rd1 : (cphi*E2i + sp2*E2e) * rd2;
    float cv_e = nz(chit * (cv + sv * t * ymu), cv);     // _mu_eff
    float ymu0 = ile ? (cphi*E2e + sp2*E2i) * rd1 : (E2i - sp2*E2e) * rd2;
    float ci_e = nz(chit * (ci + si * t * ymu0), ci);    // _mu0_eff

    // _S (shadowing)
    float ff = __expf(-2.0f * ftan(0.5f * (phi + EPSF)));
    float ci_etai = ci * rcp(etai);          // etai>0 always (all terms >=0, not all 0)
    float cv_etae = cv * rcp(etae);
    float temp = (cv_e * rcp(etae)) * ci_etai * chit;
    float shad = ile ? temp * rcp(1.0f - ff + ff * chit * ci_etai)
                     : temp * rcp(1.0f - ff + ff * chit * cv_etae);
    shad = nz(shad, 0.0f);

    // B: tan(g/2) = sqrt((1-cg)/(1+cg)) — exact half-angle
    float tg2 = sqf((1.0f - cg) * rcp(1.0f + cg));
    float B = B0[idx] * rcp(1.0f + rcp(h[idx]) * tg2) + 1.0f;
    float tmp1 = ci_e * rcp(ci_e + cv_e) * rcp(ci);

    float logi = __logf(fabsf((1.0f + ci_e) * rcp(ci_e)));
    float loge = __logf(fabsf((1.0f + cv_e) * rcp(cv_e)));

    #pragma unroll
    for (int k = 0; k < 3; ++k) {
        float wk = w[i3+k], bk = b[i3+k], ck = c[i3+k];
        float b2 = bk * bk;
        float bx = bk * cg;
        float t1 = 1.0f - 2.0f*bx + b2;      // >= (1-b)^2 >= 0.04 — positive
        float t2 = 1.0f + 2.0f*bx + b2;
        float omb2 = 1.0f - b2;
        float P = nz(ck * omb2 * rcp(t1 * sqf(t1) + 1e-6f)
                   + (1.0f - ck) * omb2 * rcp(t2 * sqf(t2) + 1e-6f), 0.0f);
        float gamma = sqf(1.0f - wk);
        float ro = (1.0f - gamma) * rcp(1.0f + gamma);
        float Hi = nz(rcp(1.0f - wk*ci_e*(ro + (1.0f - 2.0f*ro*ci_e)*0.5f*logi)), 1.0f);
        float Hv = nz(rcp(1.0f - wk*cv_e*(ro + (1.0f - 2.0f*ro*cv_e)*0.5f*loge)), 1.0f);
        float tmp2 = P * B + Hi * Hv - 1.0f;
        out[i3+k] = wk * 0.25f * tmp1 * tmp2 * shad;   // w / HPK_SCL
    }
}

extern "C" void kernel_launch(void* const* d_in, const int* in_sizes, int n_in,
                              void* d_out, int out_size, void* d_ws, size_t ws_size,
                              hipStream_t stream) {
    const float* pts2l  = (const float*)d_in[0];
    const float* pts2c  = (const float*)d_in[1];
    const float* normal = (const float*)d_in[2];
    const float* w      = (const float*)d_in[3];
    const float* b      = (const float*)d_in[4];
    const float* c      = (const float*)d_in[5];
    const float* theta  = (const float*)d_in[6];
    const float* h      = (const float*)d_in[7];
    const float* B0     = (const float*)d_in[8];
    float* out = (float*)d_out;

    int N = in_sizes[6];
    const int block = 256;
    int grid = (N + block - 1) / block;
    hapke_kernel<<<grid, block, 0, stream>>>(pts2l, pts2c, normal, w, b, c,
                                             theta, h, B0, out, N);
}